// Round 8
// baseline (1001.602 us; speedup 1.0000x reference)
//
#include <hip/hip_runtime.h>
#include <hip/hip_fp16.h>

#define N_ITEMS   100000
#define N_BASKETS 50000
#define NNZ       1000000
#define D         128

// ---------------- windowed CSR build: counting sort on key=(window,rowgroup) ----
// window = col >> 13 (8192 fp16 source rows * 256B = 2MB slice, fits XCD L2)
// rowgroup = RPW rows owned by one wave. key = w*G + (row/RPW). G = 6250 for both
// matrices (item RPW=16, basket RPW=8 -> no tail rows anywhere).
#define NBLK   256
#define TPB    256
#define CH     ((NNZ + NBLK - 1) / NBLK)
#define COLSH  13
#define G_RG   6250
#define W_B    13      // basket matrix gathers items:   cols < 100000 -> w 0..12
#define W_I    7       // item matrix gathers baskets:   cols < 50000  -> w 0..6
#define RPW_B  8
#define RPW_I  16
#define NKEY_B (W_B * G_RG)          // 81250
#define NKEY_I (W_I * G_RG)          // 43750
#define NBUK_B 318                   // ceil(81250/256)
#define NBUK_I 171                   // ceil(43750/256)
#define NKEYPAD_B (NBUK_B * 256)
#define NKEYPAD_I (NBUK_I * 256)
#define NBUK_MAX 318
#define NGRID  ((G_RG + 3) / 4)      // 1563 blocks, 4 row-groups (waves) each

__device__ __forceinline__ int chunk_of_block() {
    return ((blockIdx.x & 7) << 5) | (blockIdx.x >> 3);
}

// pass 1a: per-(chunk,bucket) key counts. LDS atomics only.
__global__ __launch_bounds__(256) void k_bucket_hist(
        const int* __restrict__ b_rows, const int* __restrict__ b_cols,
        const int* __restrict__ i_rows, const int* __restrict__ i_cols,
        int* __restrict__ tableB, int* __restrict__ tableI) {
    __shared__ int cnt[NBUK_MAX];
    int chunk = chunk_of_block();
    int s = chunk * CH, e = min(s + CH, NNZ);
    for (int j = threadIdx.x; j < NBUK_B; j += TPB) cnt[j] = 0;
    __syncthreads();
    for (int i = s + (int)threadIdx.x; i < e; i += TPB) {
        int key = (b_cols[i] >> COLSH) * G_RG + (b_rows[i] >> 3);
        atomicAdd(&cnt[key >> 8], 1);
    }
    __syncthreads();
    for (int j = threadIdx.x; j < NBUK_B; j += TPB) tableB[chunk * NBUK_B + j] = cnt[j];
    __syncthreads();
    for (int j = threadIdx.x; j < NBUK_I; j += TPB) cnt[j] = 0;
    __syncthreads();
    for (int i = s + (int)threadIdx.x; i < e; i += TPB) {
        int key = (i_cols[i] >> COLSH) * G_RG + (i_rows[i] >> 4);
        atomicAdd(&cnt[key >> 8], 1);
    }
    __syncthreads();
    for (int j = threadIdx.x; j < NBUK_I; j += TPB) tableI[chunk * NBUK_I + j] = cnt[j];
}

// pass 2a: per-bucket exclusive scan over the 256 chunk counts; bucket total out.
__global__ __launch_bounds__(256) void k_col_scan(int* __restrict__ tableB,
                                                  int* __restrict__ tableI,
                                                  int* __restrict__ totB,
                                                  int* __restrict__ totI) {
    __shared__ int lds[NBLK];
    int id = blockIdx.x;
    int* tbl; int* tot; int b; int nbuk;
    if (id < NBUK_B) { tbl = tableB; tot = totB; b = id;          nbuk = NBUK_B; }
    else             { tbl = tableI; tot = totI; b = id - NBUK_B; nbuk = NBUK_I; }
    int t = threadIdx.x;
    int v = tbl[t * nbuk + b];
    lds[t] = v;
    __syncthreads();
    for (int o = 1; o < NBLK; o <<= 1) {
        int tv = (t >= o) ? lds[t - o] : 0;
        __syncthreads();
        lds[t] += tv;
        __syncthreads();
    }
    tbl[t * nbuk + b] = lds[t] - v;
    if (t == NBLK - 1) tot[b] = lds[t];
}

// pass 2b: chunked exclusive scan of bucket totals -> bucket element bases.
__global__ __launch_bounds__(256) void k_base_scan(const int* __restrict__ totB,
                                                   const int* __restrict__ totI,
                                                   int* __restrict__ baseB,
                                                   int* __restrict__ baseI) {
    __shared__ int lds[256];
    const int* tot; int* base; int n;
    if (blockIdx.x == 0) { tot = totB; base = baseB; n = NBUK_B; }
    else                 { tot = totI; base = baseI; n = NBUK_I; }
    int t = threadIdx.x;
    int carry = 0;
    for (int c = 0; c < n; c += 256) {
        int idx = c + t;
        int v = (idx < n) ? tot[idx] : 0;
        lds[t] = v;
        __syncthreads();
        for (int o = 1; o < 256; o <<= 1) {
            int tv = (t >= o) ? lds[t - o] : 0;
            __syncthreads();
            lds[t] += tv;
            __syncthreads();
        }
        if (idx < n) base[idx] = carry + lds[t] - v;
        int tc = lds[255];
        __syncthreads();
        carry += tc;
    }
}

// pass 1b: route COO into bucket-grouped staging. ev.x packs (localrow<<20)|col.
__global__ __launch_bounds__(256) void k_route(
        const int* __restrict__ b_rows, const int* __restrict__ b_cols,
        const float* __restrict__ b_vals,
        const int* __restrict__ i_rows, const int* __restrict__ i_cols,
        const float* __restrict__ i_vals,
        const int* __restrict__ tableB, const int* __restrict__ tableI,
        const int* __restrict__ baseB, const int* __restrict__ baseI,
        int* __restrict__ stg_keyB, int2* __restrict__ stg_cvB,
        int* __restrict__ stg_keyI, int2* __restrict__ stg_cvI) {
    __shared__ int cur[NBUK_MAX];
    int chunk = chunk_of_block();
    int s = chunk * CH, e = min(s + CH, NNZ);
    for (int j = threadIdx.x; j < NBUK_B; j += TPB)
        cur[j] = baseB[j] + tableB[chunk * NBUK_B + j];
    __syncthreads();
    for (int i = s + (int)threadIdx.x; i < e; i += TPB) {
        int r = b_rows[i];
        int c = b_cols[i];
        float v = b_vals[i];
        int key = (c >> COLSH) * G_RG + (r >> 3);
        int p = atomicAdd(&cur[key >> 8], 1);   // LDS atomic
        stg_keyB[p] = key;
        stg_cvB[p] = make_int2(((r & 7) << 20) | c, __float_as_int(v));
    }
    __syncthreads();
    for (int j = threadIdx.x; j < NBUK_I; j += TPB)
        cur[j] = baseI[j] + tableI[chunk * NBUK_I + j];
    __syncthreads();
    for (int i = s + (int)threadIdx.x; i < e; i += TPB) {
        int r = i_rows[i];
        int c = i_cols[i];
        float v = i_vals[i];
        int key = (c >> COLSH) * G_RG + (r >> 4);
        int p = atomicAdd(&cur[key >> 8], 1);   // LDS atomic
        stg_keyI[p] = key;
        stg_cvI[p] = make_int2(((r & 15) << 20) | c, __float_as_int(v));
    }
}

// pass 3: per-bucket counting sort over 256 local keys -> final ev + rp2.
__global__ __launch_bounds__(256) void k_bucket_sort(
        const int* __restrict__ stg_keyB, const int2* __restrict__ stg_cvB,
        const int* __restrict__ stg_keyI, const int2* __restrict__ stg_cvI,
        const int* __restrict__ baseB, const int* __restrict__ baseI,
        const int* __restrict__ totB, const int* __restrict__ totI,
        int* __restrict__ rp2B, int* __restrict__ rp2I,
        int2* __restrict__ b_ev, int2* __restrict__ i_ev) {
    __shared__ int hist[256];
    __shared__ int scn[256];
    __shared__ int cursor[256];
    int id = blockIdx.x;
    const int* skey; const int2* scv; int* rp; int2* ev;
    const int* base; const int* tot; int b; int nbuk; int nkeypad;
    if (id < NBUK_B) {
        skey = stg_keyB; scv = stg_cvB; rp = rp2B; ev = b_ev;
        base = baseB; tot = totB; b = id; nbuk = NBUK_B; nkeypad = NKEYPAD_B;
    } else {
        skey = stg_keyI; scv = stg_cvI; rp = rp2I; ev = i_ev;
        base = baseI; tot = totI; b = id - NBUK_B; nbuk = NBUK_I; nkeypad = NKEYPAD_I;
    }
    int keybase = b << 8;
    int seg = base[b];
    int cnt = tot[b];
    int t = threadIdx.x;

    hist[t] = 0;
    __syncthreads();
    for (int i = t; i < cnt; i += TPB)
        atomicAdd(&hist[skey[seg + i] - keybase], 1);
    __syncthreads();
    int v = hist[t];
    scn[t] = v;
    __syncthreads();
    for (int o = 1; o < 256; o <<= 1) {
        int tv = (t >= o) ? scn[t - o] : 0;
        __syncthreads();
        scn[t] += tv;
        __syncthreads();
    }
    int excl = scn[t] - v;
    rp[keybase + t] = seg + excl;
    if (t == 0 && b == nbuk - 1) rp[nkeypad] = NNZ;
    cursor[t] = excl;
    __syncthreads();
    for (int i = t; i < cnt; i += TPB) {
        int key = skey[seg + i];
        int p = atomicAdd(&cursor[key - keybase], 1);   // LDS atomic
        ev[seg + p] = scv[seg + i];
    }
}

// ---------------- x -> fp16 conversion (once) ----------------
__global__ __launch_bounds__(256) void k_cvt(const float2* __restrict__ xin,
                                             __half2* __restrict__ xout) {
    const int n = N_ITEMS * D / 2;
    int i = blockIdx.x * blockDim.x + threadIdx.x;
    int stride = gridDim.x * blockDim.x;
    for (; i < n; i += stride) xout[i] = __float22half2_rn(xin[i]);
}

// ---- wave-uniform accumulator routing (lr identical across lanes; SALU switch;
//      all acc indices compile-time so acc stays in registers - rule #20 safe) ----
template<int RPW>
__device__ __forceinline__ void route_acc(float2 (&acc)[RPW], int lr, float v, float2 d) {
    switch (lr) {
#define CASE_R(i) case i: if constexpr (i < RPW) { \
        acc[i].x = fmaf(v, d.x, acc[i].x); acc[i].y = fmaf(v, d.y, acc[i].y); } break;
        CASE_R(0)  CASE_R(1)  CASE_R(2)  CASE_R(3)
        CASE_R(4)  CASE_R(5)  CASE_R(6)  CASE_R(7)
        CASE_R(8)  CASE_R(9)  CASE_R(10) CASE_R(11)
        CASE_R(12) CASE_R(13) CASE_R(14) CASE_R(15)
#undef CASE_R
    }
}

// ---------------- windowed persistent CSR SpMM, chunk-contiguous ----------------
// Wave's work per window = ONE contiguous ev chunk (avg 23/12 elems) -> full
// 8-deep gather pipeline (fixes r7's MLP collapse) while keeping window locality.
// MODE 1: basket L1: out16 = h(acc); outf  = acc
// MODE 2: basket L2: out16 = h(acc); outf += acc
// MODE 3: basket L3: out16 = h(acc); outf  = (outf+acc)/3
// MODE 0: item L1/L2: out16 = h(acc)
// MODE 4: item L3:   outf = (a0 + f(a1) + f(a2) + acc)/4
template<int MODE, int W, int RPW>
__global__ __launch_bounds__(256, 6) void k_spmm_win(
        const int* __restrict__ rp2, const int2* __restrict__ ev,
        const void* __restrict__ src,
        void* __restrict__ out16, float* __restrict__ outf,
        const float* __restrict__ a0, const void* __restrict__ a1,
        const void* __restrict__ a2) {
    __shared__ int bnd[4][2 * W];
    int wv   = threadIdx.x >> 6;
    int lane = threadIdx.x & 63;
    int g  = blockIdx.x * 4 + wv;
    int gc = min(g, G_RG - 1);
    for (int j = lane; j < 2 * W; j += 64)
        bnd[wv][j] = rp2[(j >> 1) * G_RG + gc + (j & 1)];
    __syncthreads();
    if (g >= G_RG) return;   // after barrier; no barriers below

    const char* dbase = reinterpret_cast<const char*>(src) + (size_t)lane * 4;
    float2 acc[RPW];
    #pragma unroll
    for (int i = 0; i < RPW; ++i) acc[i] = make_float2(0.f, 0.f);

#define DO_BATCH(NB) do { \
    int2 q[NB]; \
    _Pragma("unroll") for (int k = 0; k < NB; ++k) q[k] = ev[e + k]; \
    float2 dd[NB]; \
    _Pragma("unroll") for (int k = 0; k < NB; ++k) \
        dd[k] = __half22float2(*reinterpret_cast<const __half2*>( \
            dbase + ((size_t)(q[k].x & 0xFFFFF) << 8))); \
    _Pragma("unroll") for (int k = 0; k < NB; ++k) \
        route_acc<RPW>(acc, q[k].x >> 20, __int_as_float(q[k].y), dd[k]); \
} while (0)

    for (int w = 0; w < W; ++w) {
        int beg = __builtin_amdgcn_readfirstlane(bnd[wv][2 * w]);
        int end = __builtin_amdgcn_readfirstlane(bnd[wv][2 * w + 1]);
        int e = beg;
        for (; e + 8 <= end; e += 8) DO_BATCH(8);
        if (e + 4 <= end) { DO_BATCH(4); e += 4; }
        if (e + 2 <= end) { DO_BATCH(2); e += 2; }
        if (e < end)      { DO_BATCH(1); }
    }
#undef DO_BATCH

    int rbase = g * RPW;
    #pragma unroll
    for (int i = 0; i < RPW; ++i) {
        int r = rbase + i;                           // G_RG*RPW == n_rows: no tail
        size_t o = (size_t)r * 64 + (size_t)lane;    // half2 / float2 index
        float2 a = acc[i];
        if (MODE == 0 || MODE == 1 || MODE == 2 || MODE == 3) {
            reinterpret_cast<__half2*>(out16)[o] = __float22half2_rn(a);
        }
        if (MODE == 1) {
            reinterpret_cast<float2*>(outf)[o] = a;
        } else if (MODE == 2) {
            float2 s = reinterpret_cast<const float2*>(outf)[o];
            s.x += a.x; s.y += a.y;
            reinterpret_cast<float2*>(outf)[o] = s;
        } else if (MODE == 3) {
            float2 s = reinterpret_cast<const float2*>(outf)[o];
            s.x = (s.x + a.x) * (1.0f / 3.0f);
            s.y = (s.y + a.y) * (1.0f / 3.0f);
            reinterpret_cast<float2*>(outf)[o] = s;
        } else if (MODE == 4) {
            float2 s0 = reinterpret_cast<const float2*>(a0)[o];
            float2 c1 = __half22float2(reinterpret_cast<const __half2*>(a1)[o]);
            float2 c2 = __half22float2(reinterpret_cast<const __half2*>(a2)[o]);
            float2 rr;
            rr.x = (s0.x + c1.x + c2.x + a.x) * 0.25f;
            rr.y = (s0.y + c1.y + c2.y + a.y) * 0.25f;
            reinterpret_cast<float2*>(outf)[o] = rr;
        }
    }
}

extern "C" void kernel_launch(void* const* d_in, const int* in_sizes, int n_in,
                              void* d_out, int out_size, void* d_ws, size_t ws_size,
                              hipStream_t stream) {
    const float* x      = (const float*)d_in[0];
    const int*   b_rows = (const int*)  d_in[1];
    const int*   b_cols = (const int*)  d_in[2];
    const float* b_vals = (const float*)d_in[3];
    const int*   i_rows = (const int*)  d_in[4];
    const int*   i_cols = (const int*)  d_in[5];
    const float* i_vals = (const float*)d_in[6];

    float* out        = (float*)d_out;
    float* out_item   = out;                              // [N_ITEMS * D]
    float* out_basket = out + (size_t)N_ITEMS * D;        // [N_BASKETS * D]

    char* ws = (char*)d_ws;
    size_t off = 0;
    auto alloc = [&](size_t bytes) -> char* {
        char* p = ws + off;
        off = (off + bytes + 255) & ~(size_t)255;
        return p;
    };
    int*   totB      = (int*)  alloc(NBUK_B * sizeof(int));
    int*   totI      = (int*)  alloc(NBUK_I * sizeof(int));
    int*   baseB     = (int*)  alloc(NBUK_B * sizeof(int));
    int*   baseI     = (int*)  alloc(NBUK_I * sizeof(int));
    int*   rp2B      = (int*)  alloc((NKEYPAD_B + 1) * sizeof(int));  // 326 KB
    int*   rp2I      = (int*)  alloc((NKEYPAD_I + 1) * sizeof(int));  // 175 KB
    int2*  b_ev      = (int2*) alloc((size_t)NNZ * sizeof(int2));     // 8 MB
    int2*  i_ev      = (int2*) alloc((size_t)NNZ * sizeof(int2));     // 8 MB
    void*  basket16  = (void*) alloc((size_t)N_BASKETS * D * 2);      // 12.8 MB
    // region R1 (25.6 MB): tables (build) -> x16 (cvt..basketL1) -> cur2 (itemL2..)
    char*  R1        = alloc((size_t)N_ITEMS * D * 2);
    int*   tableB    = (int*)R1;                                      // 326 KB
    int*   tableI    = (int*)(R1 + (size_t)NBLK * NBUK_B * sizeof(int));
    void*  x16       = (void*)R1;
    void*  cur2_16   = (void*)R1;
    // region R2 (25.6 MB): staging (build) -> cur1 (itemL1..)
    char*  R2        = alloc((size_t)N_ITEMS * D * 2);
    int*   stg_keyB  = (int*) R2;                                     // 4 MB
    int2*  stg_cvB   = (int2*)(R2 + (size_t)NNZ * 4);                 // 8 MB
    int*   stg_keyI  = (int*) (R2 + (size_t)NNZ * 12);                // 4 MB
    int2*  stg_cvI   = (int2*)(R2 + (size_t)NNZ * 16);                // 8 MB
    void*  cur1_16   = (void*)R2;
    (void)ws_size; (void)in_sizes; (void)n_in; (void)out_size;

    // -------- atomic-free windowed CSR build --------
    k_bucket_hist<<<NBLK, TPB, 0, stream>>>(b_rows, b_cols, i_rows, i_cols,
                                            tableB, tableI);
    k_col_scan<<<NBUK_B + NBUK_I, NBLK, 0, stream>>>(tableB, tableI, totB, totI);
    k_base_scan<<<2, 256, 0, stream>>>(totB, totI, baseB, baseI);
    k_route<<<NBLK, TPB, 0, stream>>>(b_rows, b_cols, b_vals,
                                      i_rows, i_cols, i_vals,
                                      tableB, tableI, baseB, baseI,
                                      stg_keyB, stg_cvB, stg_keyI, stg_cvI);
    k_bucket_sort<<<NBUK_B + NBUK_I, 256, 0, stream>>>(stg_keyB, stg_cvB,
                                                       stg_keyI, stg_cvI,
                                                       baseB, baseI, totB, totI,
                                                       rp2B, rp2I, b_ev, i_ev);
    // x -> fp16 (tables dead after route; x16 aliases them)
    k_cvt<<<2048, 256, 0, stream>>>(reinterpret_cast<const float2*>(x),
                                    reinterpret_cast<__half2*>(x16));

    // -------- layer 1 --------
    k_spmm_win<1, W_B, RPW_B><<<NGRID, 256, 0, stream>>>(rp2B, b_ev, x16,
        basket16, out_basket, nullptr, nullptr, nullptr);
    k_spmm_win<0, W_I, RPW_I><<<NGRID, 256, 0, stream>>>(rp2I, i_ev, basket16,
        cur1_16, nullptr, nullptr, nullptr, nullptr);
    // -------- layer 2 --------
    k_spmm_win<2, W_B, RPW_B><<<NGRID, 256, 0, stream>>>(rp2B, b_ev, cur1_16,
        basket16, out_basket, nullptr, nullptr, nullptr);
    k_spmm_win<0, W_I, RPW_I><<<NGRID, 256, 0, stream>>>(rp2I, i_ev, basket16,
        cur2_16, nullptr, nullptr, nullptr, nullptr);
    // -------- layer 3 --------
    k_spmm_win<3, W_B, RPW_B><<<NGRID, 256, 0, stream>>>(rp2B, b_ev, cur2_16,
        basket16, out_basket, nullptr, nullptr, nullptr);
    k_spmm_win<4, W_I, RPW_I><<<NGRID, 256, 0, stream>>>(rp2I, i_ev, basket16,
        nullptr, out_item, x, cur1_16, cur2_16);
}

// Round 9
// 303.665 us; speedup vs baseline: 3.2984x; 3.2984x over previous
//
#include <hip/hip_runtime.h>
#include <hip/hip_fp16.h>

#define N_ITEMS   100000
#define N_BASKETS 50000
#define NNZ       1000000
#define D         128

// ---------------- windowed CSR build: counting sort on key=(window,rowgroup) ----
// window = col >> 13 (8192 fp16 source rows * 256B = 2MB slice, fits XCD L2)
// rowgroup = 8 rows owned by one wave. key = w*G + (row>>3).
#define NBLK   256
#define TPB    256
#define CH     ((NNZ + NBLK - 1) / NBLK)
#define COLSH  13
#define RPW    8
#define G_B    6250     // 50000/8
#define G_I    12500    // 100000/8
#define W_B    13       // basket matrix gathers items:   cols < 100000 -> w 0..12
#define W_I    7        // item matrix gathers baskets:   cols < 50000  -> w 0..6
#define NKEY_B (W_B * G_B)           // 81250
#define NKEY_I (W_I * G_I)           // 87500
#define NBUK_B 318                   // ceil(81250/256)
#define NBUK_I 342                   // ceil(87500/256)
#define NKEYPAD_B (NBUK_B * 256)
#define NKEYPAD_I (NBUK_I * 256)
#define NBUK_MAX 342

__device__ __forceinline__ int chunk_of_block() {
    return ((blockIdx.x & 7) << 5) | (blockIdx.x >> 3);
}

// pass 1a: per-(chunk,bucket) key counts. LDS atomics only.
__global__ __launch_bounds__(256) void k_bucket_hist(
        const int* __restrict__ b_rows, const int* __restrict__ b_cols,
        const int* __restrict__ i_rows, const int* __restrict__ i_cols,
        int* __restrict__ tableB, int* __restrict__ tableI) {
    __shared__ int cnt[NBUK_MAX];
    int chunk = chunk_of_block();
    int s = chunk * CH, e = min(s + CH, NNZ);
    for (int j = threadIdx.x; j < NBUK_B; j += TPB) cnt[j] = 0;
    __syncthreads();
    for (int i = s + (int)threadIdx.x; i < e; i += TPB) {
        int key = (b_cols[i] >> COLSH) * G_B + (b_rows[i] >> 3);
        atomicAdd(&cnt[key >> 8], 1);
    }
    __syncthreads();
    for (int j = threadIdx.x; j < NBUK_B; j += TPB) tableB[chunk * NBUK_B + j] = cnt[j];
    __syncthreads();
    for (int j = threadIdx.x; j < NBUK_I; j += TPB) cnt[j] = 0;
    __syncthreads();
    for (int i = s + (int)threadIdx.x; i < e; i += TPB) {
        int key = (i_cols[i] >> COLSH) * G_I + (i_rows[i] >> 3);
        atomicAdd(&cnt[key >> 8], 1);
    }
    __syncthreads();
    for (int j = threadIdx.x; j < NBUK_I; j += TPB) tableI[chunk * NBUK_I + j] = cnt[j];
}

// pass 2a: per-bucket exclusive scan over the 256 chunk counts; bucket total out.
__global__ __launch_bounds__(256) void k_col_scan(int* __restrict__ tableB,
                                                  int* __restrict__ tableI,
                                                  int* __restrict__ totB,
                                                  int* __restrict__ totI) {
    __shared__ int lds[NBLK];
    int id = blockIdx.x;
    int* tbl; int* tot; int b; int nbuk;
    if (id < NBUK_B) { tbl = tableB; tot = totB; b = id;          nbuk = NBUK_B; }
    else             { tbl = tableI; tot = totI; b = id - NBUK_B; nbuk = NBUK_I; }
    int t = threadIdx.x;
    int v = tbl[t * nbuk + b];
    lds[t] = v;
    __syncthreads();
    for (int o = 1; o < NBLK; o <<= 1) {
        int tv = (t >= o) ? lds[t - o] : 0;
        __syncthreads();
        lds[t] += tv;
        __syncthreads();
    }
    tbl[t * nbuk + b] = lds[t] - v;
    if (t == NBLK - 1) tot[b] = lds[t];
}

// pass 2b: chunked exclusive scan of bucket totals -> bucket element bases.
__global__ __launch_bounds__(256) void k_base_scan(const int* __restrict__ totB,
                                                   const int* __restrict__ totI,
                                                   int* __restrict__ baseB,
                                                   int* __restrict__ baseI) {
    __shared__ int lds[256];
    const int* tot; int* base; int n;
    if (blockIdx.x == 0) { tot = totB; base = baseB; n = NBUK_B; }
    else                 { tot = totI; base = baseI; n = NBUK_I; }
    int t = threadIdx.x;
    int carry = 0;
    for (int c = 0; c < n; c += 256) {
        int idx = c + t;
        int v = (idx < n) ? tot[idx] : 0;
        lds[t] = v;
        __syncthreads();
        for (int o = 1; o < 256; o <<= 1) {
            int tv = (t >= o) ? lds[t - o] : 0;
            __syncthreads();
            lds[t] += tv;
            __syncthreads();
        }
        if (idx < n) base[idx] = carry + lds[t] - v;
        int tc = lds[255];
        __syncthreads();
        carry += tc;
    }
}

// pass 1b: route COO into bucket-grouped staging. ev.x packs (localrow<<20)|col.
__global__ __launch_bounds__(256) void k_route(
        const int* __restrict__ b_rows, const int* __restrict__ b_cols,
        const float* __restrict__ b_vals,
        const int* __restrict__ i_rows, const int* __restrict__ i_cols,
        const float* __restrict__ i_vals,
        const int* __restrict__ tableB, const int* __restrict__ tableI,
        const int* __restrict__ baseB, const int* __restrict__ baseI,
        int* __restrict__ stg_keyB, int2* __restrict__ stg_cvB,
        int* __restrict__ stg_keyI, int2* __restrict__ stg_cvI) {
    __shared__ int cur[NBUK_MAX];
    int chunk = chunk_of_block();
    int s = chunk * CH, e = min(s + CH, NNZ);
    for (int j = threadIdx.x; j < NBUK_B; j += TPB)
        cur[j] = baseB[j] + tableB[chunk * NBUK_B + j];
    __syncthreads();
    for (int i = s + (int)threadIdx.x; i < e; i += TPB) {
        int r = b_rows[i];
        int c = b_cols[i];
        float v = b_vals[i];
        int key = (c >> COLSH) * G_B + (r >> 3);
        int p = atomicAdd(&cur[key >> 8], 1);   // LDS atomic
        stg_keyB[p] = key;
        stg_cvB[p] = make_int2(((r & 7) << 20) | c, __float_as_int(v));
    }
    __syncthreads();
    for (int j = threadIdx.x; j < NBUK_I; j += TPB)
        cur[j] = baseI[j] + tableI[chunk * NBUK_I + j];
    __syncthreads();
    for (int i = s + (int)threadIdx.x; i < e; i += TPB) {
        int r = i_rows[i];
        int c = i_cols[i];
        float v = i_vals[i];
        int key = (c >> COLSH) * G_I + (r >> 3);
        int p = atomicAdd(&cur[key >> 8], 1);   // LDS atomic
        stg_keyI[p] = key;
        stg_cvI[p] = make_int2(((r & 7) << 20) | c, __float_as_int(v));
    }
}

// pass 3: per-bucket counting sort over 256 local keys -> final ev + rp2.
__global__ __launch_bounds__(256) void k_bucket_sort(
        const int* __restrict__ stg_keyB, const int2* __restrict__ stg_cvB,
        const int* __restrict__ stg_keyI, const int2* __restrict__ stg_cvI,
        const int* __restrict__ baseB, const int* __restrict__ baseI,
        const int* __restrict__ totB, const int* __restrict__ totI,
        int* __restrict__ rp2B, int* __restrict__ rp2I,
        int2* __restrict__ b_ev, int2* __restrict__ i_ev) {
    __shared__ int hist[256];
    __shared__ int scn[256];
    __shared__ int cursor[256];
    int id = blockIdx.x;
    const int* skey; const int2* scv; int* rp; int2* ev;
    const int* base; const int* tot; int b; int nbuk; int nkeypad;
    if (id < NBUK_B) {
        skey = stg_keyB; scv = stg_cvB; rp = rp2B; ev = b_ev;
        base = baseB; tot = totB; b = id; nbuk = NBUK_B; nkeypad = NKEYPAD_B;
    } else {
        skey = stg_keyI; scv = stg_cvI; rp = rp2I; ev = i_ev;
        base = baseI; tot = totI; b = id - NBUK_B; nbuk = NBUK_I; nkeypad = NKEYPAD_I;
    }
    int keybase = b << 8;
    int seg = base[b];
    int cnt = tot[b];
    int t = threadIdx.x;

    hist[t] = 0;
    __syncthreads();
    for (int i = t; i < cnt; i += TPB)
        atomicAdd(&hist[skey[seg + i] - keybase], 1);
    __syncthreads();
    int v = hist[t];
    scn[t] = v;
    __syncthreads();
    for (int o = 1; o < 256; o <<= 1) {
        int tv = (t >= o) ? scn[t - o] : 0;
        __syncthreads();
        scn[t] += tv;
        __syncthreads();
    }
    int excl = scn[t] - v;
    rp[keybase + t] = seg + excl;
    if (t == 0 && b == nbuk - 1) rp[nkeypad] = NNZ;
    cursor[t] = excl;
    __syncthreads();
    for (int i = t; i < cnt; i += TPB) {
        int key = skey[seg + i];
        int p = atomicAdd(&cursor[key - keybase], 1);   // LDS atomic
        ev[seg + p] = scv[seg + i];
    }
}

// ---------------- x -> fp16 conversion (once) ----------------
__global__ __launch_bounds__(256) void k_cvt(const float2* __restrict__ xin,
                                             __half2* __restrict__ xout) {
    const int n = N_ITEMS * D / 2;
    int i = blockIdx.x * blockDim.x + threadIdx.x;
    int stride = gridDim.x * blockDim.x;
    for (; i < n; i += stride) xout[i] = __float22half2_rn(xin[i]);
}

// ---------------- windowed CSR SpMM with LDS accumulators ----------------
// Wave's work per window = one contiguous ev chunk (8-deep gather batches, full
// MLP). Accumulator routing uses runtime-indexed LDS (NOT registers - r8's
// scratch disaster): acc[wave][localrow][lane] float2; 64 lanes x 8B contiguous
// per RMW = conflict-free. Each wave owns its acc region -> no barriers at all.
// MODE 1: basket L1: out16 = h(acc); outf  = acc
// MODE 2: basket L2: out16 = h(acc); outf += acc
// MODE 3: basket L3: out16 = h(acc); outf  = (outf+acc)/3
// MODE 0: item L1/L2: out16 = h(acc)
// MODE 4: item L3:   outf = (a0 + f(a1) + f(a2) + acc)/4
template<int MODE, int W, int G>
__global__ __launch_bounds__(256, 6) void k_spmm_lds(
        const int* __restrict__ rp2, const int2* __restrict__ ev,
        const void* __restrict__ src,
        void* __restrict__ out16, float* __restrict__ outf,
        const float* __restrict__ a0, const void* __restrict__ a1,
        const void* __restrict__ a2) {
    __shared__ float2 accL[4][RPW][64];   // 16 KB
    __shared__ int bnd[4][2 * W];
    int wv   = threadIdx.x >> 6;
    int lane = threadIdx.x & 63;
    int g = blockIdx.x * 4 + wv;
    if (g >= G) return;                   // no barriers in this kernel
    for (int j = lane; j < 2 * W; j += 64)
        bnd[wv][j] = rp2[(j >> 1) * G + g + (j & 1)];
    #pragma unroll
    for (int i = 0; i < RPW; ++i) accL[wv][i][lane] = make_float2(0.f, 0.f);

    const char* dbase = reinterpret_cast<const char*>(src) + (size_t)lane * 4;

#define DO_BATCH(NB) do { \
    int2 q[NB]; \
    _Pragma("unroll") for (int k = 0; k < NB; ++k) q[k] = ev[e + k]; \
    float2 dd[NB]; \
    _Pragma("unroll") for (int k = 0; k < NB; ++k) \
        dd[k] = __half22float2(*reinterpret_cast<const __half2*>( \
            dbase + ((size_t)(q[k].x & 0xFFFFF) << 8))); \
    _Pragma("unroll") for (int k = 0; k < NB; ++k) { \
        int lr = q[k].x >> 20; \
        float v = __int_as_float(q[k].y); \
        float2 t = accL[wv][lr][lane]; \
        t.x = fmaf(v, dd[k].x, t.x); t.y = fmaf(v, dd[k].y, t.y); \
        accL[wv][lr][lane] = t; \
    } \
} while (0)

    for (int w = 0; w < W; ++w) {
        int beg = __builtin_amdgcn_readfirstlane(bnd[wv][2 * w]);
        int end = __builtin_amdgcn_readfirstlane(bnd[wv][2 * w + 1]);
        int e = beg;
        for (; e + 8 <= end; e += 8) DO_BATCH(8);
        if (e + 4 <= end) { DO_BATCH(4); e += 4; }
        if (e + 2 <= end) { DO_BATCH(2); e += 2; }
        if (e < end)      { DO_BATCH(1); }
    }
#undef DO_BATCH

    int rbase = g * RPW;
    #pragma unroll
    for (int i = 0; i < RPW; ++i) {
        int r = rbase + i;                           // G*RPW == n_rows: no tail
        size_t o = (size_t)r * 64 + (size_t)lane;    // half2 / float2 index
        float2 a = accL[wv][i][lane];
        if (MODE == 0 || MODE == 1 || MODE == 2 || MODE == 3) {
            reinterpret_cast<__half2*>(out16)[o] = __float22half2_rn(a);
        }
        if (MODE == 1) {
            reinterpret_cast<float2*>(outf)[o] = a;
        } else if (MODE == 2) {
            float2 s = reinterpret_cast<const float2*>(outf)[o];
            s.x += a.x; s.y += a.y;
            reinterpret_cast<float2*>(outf)[o] = s;
        } else if (MODE == 3) {
            float2 s = reinterpret_cast<const float2*>(outf)[o];
            s.x = (s.x + a.x) * (1.0f / 3.0f);
            s.y = (s.y + a.y) * (1.0f / 3.0f);
            reinterpret_cast<float2*>(outf)[o] = s;
        } else if (MODE == 4) {
            float2 s0 = reinterpret_cast<const float2*>(a0)[o];
            float2 c1 = __half22float2(reinterpret_cast<const __half2*>(a1)[o]);
            float2 c2 = __half22float2(reinterpret_cast<const __half2*>(a2)[o]);
            float2 rr;
            rr.x = (s0.x + c1.x + c2.x + a.x) * 0.25f;
            rr.y = (s0.y + c1.y + c2.y + a.y) * 0.25f;
            reinterpret_cast<float2*>(outf)[o] = rr;
        }
    }
}

extern "C" void kernel_launch(void* const* d_in, const int* in_sizes, int n_in,
                              void* d_out, int out_size, void* d_ws, size_t ws_size,
                              hipStream_t stream) {
    const float* x      = (const float*)d_in[0];
    const int*   b_rows = (const int*)  d_in[1];
    const int*   b_cols = (const int*)  d_in[2];
    const float* b_vals = (const float*)d_in[3];
    const int*   i_rows = (const int*)  d_in[4];
    const int*   i_cols = (const int*)  d_in[5];
    const float* i_vals = (const float*)d_in[6];

    float* out        = (float*)d_out;
    float* out_item   = out;                              // [N_ITEMS * D]
    float* out_basket = out + (size_t)N_ITEMS * D;        // [N_BASKETS * D]

    char* ws = (char*)d_ws;
    size_t off = 0;
    auto alloc = [&](size_t bytes) -> char* {
        char* p = ws + off;
        off = (off + bytes + 255) & ~(size_t)255;
        return p;
    };
    int*   totB      = (int*)  alloc(NBUK_B * sizeof(int));
    int*   totI      = (int*)  alloc(NBUK_I * sizeof(int));
    int*   baseB     = (int*)  alloc(NBUK_B * sizeof(int));
    int*   baseI     = (int*)  alloc(NBUK_I * sizeof(int));
    int*   rp2B      = (int*)  alloc((NKEYPAD_B + 1) * sizeof(int));
    int*   rp2I      = (int*)  alloc((NKEYPAD_I + 1) * sizeof(int));
    int2*  b_ev      = (int2*) alloc((size_t)NNZ * sizeof(int2));     // 8 MB
    int2*  i_ev      = (int2*) alloc((size_t)NNZ * sizeof(int2));     // 8 MB
    void*  basket16  = (void*) alloc((size_t)N_BASKETS * D * 2);      // 12.8 MB
    // region R1 (25.6 MB): tables (build) -> x16 (cvt..basketL1) -> cur2 (itemL2..)
    char*  R1        = alloc((size_t)N_ITEMS * D * 2);
    int*   tableB    = (int*)R1;
    int*   tableI    = (int*)(R1 + (size_t)NBLK * NBUK_B * sizeof(int));
    void*  x16       = (void*)R1;
    void*  cur2_16   = (void*)R1;
    // region R2 (25.6 MB): staging (build) -> cur1 (itemL1..)
    char*  R2        = alloc((size_t)N_ITEMS * D * 2);
    int*   stg_keyB  = (int*) R2;
    int2*  stg_cvB   = (int2*)(R2 + (size_t)NNZ * 4);
    int*   stg_keyI  = (int*) (R2 + (size_t)NNZ * 12);
    int2*  stg_cvI   = (int2*)(R2 + (size_t)NNZ * 16);
    void*  cur1_16   = (void*)R2;
    (void)ws_size; (void)in_sizes; (void)n_in; (void)out_size;

    // -------- atomic-free windowed CSR build --------
    k_bucket_hist<<<NBLK, TPB, 0, stream>>>(b_rows, b_cols, i_rows, i_cols,
                                            tableB, tableI);
    k_col_scan<<<NBUK_B + NBUK_I, NBLK, 0, stream>>>(tableB, tableI, totB, totI);
    k_base_scan<<<2, 256, 0, stream>>>(totB, totI, baseB, baseI);
    k_route<<<NBLK, TPB, 0, stream>>>(b_rows, b_cols, b_vals,
                                      i_rows, i_cols, i_vals,
                                      tableB, tableI, baseB, baseI,
                                      stg_keyB, stg_cvB, stg_keyI, stg_cvI);
    k_bucket_sort<<<NBUK_B + NBUK_I, 256, 0, stream>>>(stg_keyB, stg_cvB,
                                                       stg_keyI, stg_cvI,
                                                       baseB, baseI, totB, totI,
                                                       rp2B, rp2I, b_ev, i_ev);
    // x -> fp16 (tables dead after route; x16 aliases them)
    k_cvt<<<2048, 256, 0, stream>>>(reinterpret_cast<const float2*>(x),
                                    reinterpret_cast<__half2*>(x16));

    const int NG_B = (G_B + 3) / 4;   // 1563 blocks
    const int NG_I = (G_I + 3) / 4;   // 3125 blocks

    // -------- layer 1 --------
    k_spmm_lds<1, W_B, G_B><<<NG_B, 256, 0, stream>>>(rp2B, b_ev, x16,
        basket16, out_basket, nullptr, nullptr, nullptr);
    k_spmm_lds<0, W_I, G_I><<<NG_I, 256, 0, stream>>>(rp2I, i_ev, basket16,
        cur1_16, nullptr, nullptr, nullptr, nullptr);
    // -------- layer 2 --------
    k_spmm_lds<2, W_B, G_B><<<NG_B, 256, 0, stream>>>(rp2B, b_ev, cur1_16,
        basket16, out_basket, nullptr, nullptr, nullptr);
    k_spmm_lds<0, W_I, G_I><<<NG_I, 256, 0, stream>>>(rp2I, i_ev, basket16,
        cur2_16, nullptr, nullptr, nullptr, nullptr);
    // -------- layer 3 --------
    k_spmm_lds<3, W_B, G_B><<<NG_B, 256, 0, stream>>>(rp2B, b_ev, cur2_16,
        basket16, out_basket, nullptr, nullptr, nullptr);
    k_spmm_lds<4, W_I, G_I><<<NG_I, 256, 0, stream>>>(rp2I, i_ev, basket16,
        nullptr, out_item, x, cur1_16, cur2_16);
}

// Round 10
// 299.961 us; speedup vs baseline: 3.3391x; 1.0123x over previous
//
#include <hip/hip_runtime.h>
#include <hip/hip_fp16.h>

#define N_ITEMS   100000
#define N_BASKETS 50000
#define NNZ       1000000
#define D         128

// ---------------- windowed CSR build: counting sort on key=(window,rowgroup) ----
// window = col >> 13 (8192 fp16 source rows * 256B = 2MB slice, fits XCD L2)
// rowgroup = 8 rows owned by one wave. key = w*G + (row>>3).
#define NBLK   256
#define TPB    256
#define CH     ((NNZ + NBLK - 1) / NBLK)
#define COLSH  13
#define RPW    8
#define G_B    6250     // 50000/8
#define G_I    12500    // 100000/8
#define W_B    13       // basket matrix gathers items:   cols < 100000 -> w 0..12
#define W_I    7        // item matrix gathers baskets:   cols < 50000  -> w 0..6
#define NKEY_B (W_B * G_B)           // 81250
#define NKEY_I (W_I * G_I)           // 87500
#define NBUK_B 318                   // ceil(81250/256)
#define NBUK_I 342                   // ceil(87500/256)
#define NKEYPAD_B (NBUK_B * 256)
#define NKEYPAD_I (NBUK_I * 256)
#define NBUK_MAX 342

__device__ __forceinline__ int chunk_of_block() {
    return ((blockIdx.x & 7) << 5) | (blockIdx.x >> 3);
}

// pass 1a: per-(chunk,bucket) key counts. LDS atomics only.
__global__ __launch_bounds__(256) void k_bucket_hist(
        const int* __restrict__ b_rows, const int* __restrict__ b_cols,
        const int* __restrict__ i_rows, const int* __restrict__ i_cols,
        int* __restrict__ tableB, int* __restrict__ tableI) {
    __shared__ int cnt[NBUK_MAX];
    int chunk = chunk_of_block();
    int s = chunk * CH, e = min(s + CH, NNZ);
    for (int j = threadIdx.x; j < NBUK_B; j += TPB) cnt[j] = 0;
    __syncthreads();
    for (int i = s + (int)threadIdx.x; i < e; i += TPB) {
        int key = (b_cols[i] >> COLSH) * G_B + (b_rows[i] >> 3);
        atomicAdd(&cnt[key >> 8], 1);
    }
    __syncthreads();
    for (int j = threadIdx.x; j < NBUK_B; j += TPB) tableB[chunk * NBUK_B + j] = cnt[j];
    __syncthreads();
    for (int j = threadIdx.x; j < NBUK_I; j += TPB) cnt[j] = 0;
    __syncthreads();
    for (int i = s + (int)threadIdx.x; i < e; i += TPB) {
        int key = (i_cols[i] >> COLSH) * G_I + (i_rows[i] >> 3);
        atomicAdd(&cnt[key >> 8], 1);
    }
    __syncthreads();
    for (int j = threadIdx.x; j < NBUK_I; j += TPB) tableI[chunk * NBUK_I + j] = cnt[j];
}

// pass 2a: per-bucket exclusive scan over the 256 chunk counts; bucket total out.
__global__ __launch_bounds__(256) void k_col_scan(int* __restrict__ tableB,
                                                  int* __restrict__ tableI,
                                                  int* __restrict__ totB,
                                                  int* __restrict__ totI) {
    __shared__ int lds[NBLK];
    int id = blockIdx.x;
    int* tbl; int* tot; int b; int nbuk;
    if (id < NBUK_B) { tbl = tableB; tot = totB; b = id;          nbuk = NBUK_B; }
    else             { tbl = tableI; tot = totI; b = id - NBUK_B; nbuk = NBUK_I; }
    int t = threadIdx.x;
    int v = tbl[t * nbuk + b];
    lds[t] = v;
    __syncthreads();
    for (int o = 1; o < NBLK; o <<= 1) {
        int tv = (t >= o) ? lds[t - o] : 0;
        __syncthreads();
        lds[t] += tv;
        __syncthreads();
    }
    tbl[t * nbuk + b] = lds[t] - v;
    if (t == NBLK - 1) tot[b] = lds[t];
}

// pass 2b: chunked exclusive scan of bucket totals -> bucket element bases.
__global__ __launch_bounds__(256) void k_base_scan(const int* __restrict__ totB,
                                                   const int* __restrict__ totI,
                                                   int* __restrict__ baseB,
                                                   int* __restrict__ baseI) {
    __shared__ int lds[256];
    const int* tot; int* base; int n;
    if (blockIdx.x == 0) { tot = totB; base = baseB; n = NBUK_B; }
    else                 { tot = totI; base = baseI; n = NBUK_I; }
    int t = threadIdx.x;
    int carry = 0;
    for (int c = 0; c < n; c += 256) {
        int idx = c + t;
        int v = (idx < n) ? tot[idx] : 0;
        lds[t] = v;
        __syncthreads();
        for (int o = 1; o < 256; o <<= 1) {
            int tv = (t >= o) ? lds[t - o] : 0;
            __syncthreads();
            lds[t] += tv;
            __syncthreads();
        }
        if (idx < n) base[idx] = carry + lds[t] - v;
        int tc = lds[255];
        __syncthreads();
        carry += tc;
    }
}

// pass 1b: route COO into bucket-grouped staging. ev.x packs (localrow<<20)|col.
__global__ __launch_bounds__(256) void k_route(
        const int* __restrict__ b_rows, const int* __restrict__ b_cols,
        const float* __restrict__ b_vals,
        const int* __restrict__ i_rows, const int* __restrict__ i_cols,
        const float* __restrict__ i_vals,
        const int* __restrict__ tableB, const int* __restrict__ tableI,
        const int* __restrict__ baseB, const int* __restrict__ baseI,
        int* __restrict__ stg_keyB, int2* __restrict__ stg_cvB,
        int* __restrict__ stg_keyI, int2* __restrict__ stg_cvI) {
    __shared__ int cur[NBUK_MAX];
    int chunk = chunk_of_block();
    int s = chunk * CH, e = min(s + CH, NNZ);
    for (int j = threadIdx.x; j < NBUK_B; j += TPB)
        cur[j] = baseB[j] + tableB[chunk * NBUK_B + j];
    __syncthreads();
    for (int i = s + (int)threadIdx.x; i < e; i += TPB) {
        int r = b_rows[i];
        int c = b_cols[i];
        float v = b_vals[i];
        int key = (c >> COLSH) * G_B + (r >> 3);
        int p = atomicAdd(&cur[key >> 8], 1);   // LDS atomic
        stg_keyB[p] = key;
        stg_cvB[p] = make_int2(((r & 7) << 20) | c, __float_as_int(v));
    }
    __syncthreads();
    for (int j = threadIdx.x; j < NBUK_I; j += TPB)
        cur[j] = baseI[j] + tableI[chunk * NBUK_I + j];
    __syncthreads();
    for (int i = s + (int)threadIdx.x; i < e; i += TPB) {
        int r = i_rows[i];
        int c = i_cols[i];
        float v = i_vals[i];
        int key = (c >> COLSH) * G_I + (r >> 3);
        int p = atomicAdd(&cur[key >> 8], 1);   // LDS atomic
        stg_keyI[p] = key;
        stg_cvI[p] = make_int2(((r & 7) << 20) | c, __float_as_int(v));
    }
}

// pass 3: per-bucket counting sort over 256 local keys -> final ev + rp2.
__global__ __launch_bounds__(256) void k_bucket_sort(
        const int* __restrict__ stg_keyB, const int2* __restrict__ stg_cvB,
        const int* __restrict__ stg_keyI, const int2* __restrict__ stg_cvI,
        const int* __restrict__ baseB, const int* __restrict__ baseI,
        const int* __restrict__ totB, const int* __restrict__ totI,
        int* __restrict__ rp2B, int* __restrict__ rp2I,
        int2* __restrict__ b_ev, int2* __restrict__ i_ev) {
    __shared__ int hist[256];
    __shared__ int scn[256];
    __shared__ int cursor[256];
    int id = blockIdx.x;
    const int* skey; const int2* scv; int* rp; int2* ev;
    const int* base; const int* tot; int b; int nbuk; int nkeypad;
    if (id < NBUK_B) {
        skey = stg_keyB; scv = stg_cvB; rp = rp2B; ev = b_ev;
        base = baseB; tot = totB; b = id; nbuk = NBUK_B; nkeypad = NKEYPAD_B;
    } else {
        skey = stg_keyI; scv = stg_cvI; rp = rp2I; ev = i_ev;
        base = baseI; tot = totI; b = id - NBUK_B; nbuk = NBUK_I; nkeypad = NKEYPAD_I;
    }
    int keybase = b << 8;
    int seg = base[b];
    int cnt = tot[b];
    int t = threadIdx.x;

    hist[t] = 0;
    __syncthreads();
    for (int i = t; i < cnt; i += TPB)
        atomicAdd(&hist[skey[seg + i] - keybase], 1);
    __syncthreads();
    int v = hist[t];
    scn[t] = v;
    __syncthreads();
    for (int o = 1; o < 256; o <<= 1) {
        int tv = (t >= o) ? scn[t - o] : 0;
        __syncthreads();
        scn[t] += tv;
        __syncthreads();
    }
    int excl = scn[t] - v;
    rp[keybase + t] = seg + excl;
    if (t == 0 && b == nbuk - 1) rp[nkeypad] = NNZ;
    cursor[t] = excl;
    __syncthreads();
    for (int i = t; i < cnt; i += TPB) {
        int key = skey[seg + i];
        int p = atomicAdd(&cursor[key - keybase], 1);   // LDS atomic
        ev[seg + p] = scv[seg + i];
    }
}

// ---------------- x -> fp16 conversion (once) ----------------
__global__ __launch_bounds__(256) void k_cvt(const float2* __restrict__ xin,
                                             __half2* __restrict__ xout) {
    const int n = N_ITEMS * D / 2;
    int i = blockIdx.x * blockDim.x + threadIdx.x;
    int stride = gridDim.x * blockDim.x;
    for (; i < n; i += stride) xout[i] = __float22half2_rn(xin[i]);
}

// ---------------- windowed CSR SpMM with LDS accumulators ----------------
// Wave's work per window = one contiguous ev chunk (8-deep gather batches, full
// MLP). Accumulator routing via runtime-indexed LDS (registers would spill to
// scratch - r8). 8 blocks/CU: 135KB LDS, VGPR<=64 -> full 32-wave occupancy cap.
// MODE 0: out16 = h(acc)                                  (basket L2, item L1/L2)
// MODE 1: out16 = h(acc); outf = acc                      (basket L1)
// MODE 5: out16 = h(acc); outf = (outf + f(a1) + acc)/3   (basket L3, deferred sum)
// MODE 4: outf = (a0 + f(a1) + f(a2) + acc)/4             (item L3, final)
template<int MODE, int W, int G>
__global__ __launch_bounds__(256, 8) void k_spmm_lds(
        const int* __restrict__ rp2, const int2* __restrict__ ev,
        const void* __restrict__ src,
        void* __restrict__ out16, float* __restrict__ outf,
        const float* __restrict__ a0, const void* __restrict__ a1,
        const void* __restrict__ a2) {
    __shared__ float2 accL[4][RPW][64];   // 16 KB
    __shared__ int bnd[4][2 * W];
    int wv   = threadIdx.x >> 6;
    int lane = threadIdx.x & 63;
    int g = blockIdx.x * 4 + wv;
    if (g >= G) return;                   // no barriers in this kernel
    for (int j = lane; j < 2 * W; j += 64)
        bnd[wv][j] = rp2[(j >> 1) * G + g + (j & 1)];
    #pragma unroll
    for (int i = 0; i < RPW; ++i) accL[wv][i][lane] = make_float2(0.f, 0.f);

    const char* dbase = reinterpret_cast<const char*>(src) + (size_t)lane * 4;

#define DO_BATCH(NB) do { \
    int2 q[NB]; \
    _Pragma("unroll") for (int k = 0; k < NB; ++k) q[k] = ev[e + k]; \
    float2 dd[NB]; \
    _Pragma("unroll") for (int k = 0; k < NB; ++k) \
        dd[k] = __half22float2(*reinterpret_cast<const __half2*>( \
            dbase + ((size_t)(q[k].x & 0xFFFFF) << 8))); \
    _Pragma("unroll") for (int k = 0; k < NB; ++k) { \
        int lr = q[k].x >> 20; \
        float v = __int_as_float(q[k].y); \
        float2 t = accL[wv][lr][lane]; \
        t.x = fmaf(v, dd[k].x, t.x); t.y = fmaf(v, dd[k].y, t.y); \
        accL[wv][lr][lane] = t; \
    } \
} while (0)

    for (int w = 0; w < W; ++w) {
        int beg = __builtin_amdgcn_readfirstlane(bnd[wv][2 * w]);
        int end = __builtin_amdgcn_readfirstlane(bnd[wv][2 * w + 1]);
        int e = beg;
        for (; e + 8 <= end; e += 8) DO_BATCH(8);
        if (e + 4 <= end) { DO_BATCH(4); e += 4; }
        if (e + 2 <= end) { DO_BATCH(2); e += 2; }
        if (e < end)      { DO_BATCH(1); }
    }
#undef DO_BATCH

    int rbase = g * RPW;
    #pragma unroll
    for (int i = 0; i < RPW; ++i) {
        int r = rbase + i;                           // G*RPW == n_rows: no tail
        size_t o = (size_t)r * 64 + (size_t)lane;    // half2 / float2 index
        float2 a = accL[wv][i][lane];
        if (MODE == 0 || MODE == 1 || MODE == 5) {
            reinterpret_cast<__half2*>(out16)[o] = __float22half2_rn(a);
        }
        if (MODE == 1) {
            reinterpret_cast<float2*>(outf)[o] = a;
        } else if (MODE == 5) {
            float2 s = reinterpret_cast<const float2*>(outf)[o];
            float2 c1 = __half22float2(reinterpret_cast<const __half2*>(a1)[o]);
            s.x = (s.x + c1.x + a.x) * (1.0f / 3.0f);
            s.y = (s.y + c1.y + a.y) * (1.0f / 3.0f);
            reinterpret_cast<float2*>(outf)[o] = s;
        } else if (MODE == 4) {
            float2 s0 = reinterpret_cast<const float2*>(a0)[o];
            float2 c1 = __half22float2(reinterpret_cast<const __half2*>(a1)[o]);
            float2 c2 = __half22float2(reinterpret_cast<const __half2*>(a2)[o]);
            float2 rr;
            rr.x = (s0.x + c1.x + c2.x + a.x) * 0.25f;
            rr.y = (s0.y + c1.y + c2.y + a.y) * 0.25f;
            reinterpret_cast<float2*>(outf)[o] = rr;
        }
    }
}

extern "C" void kernel_launch(void* const* d_in, const int* in_sizes, int n_in,
                              void* d_out, int out_size, void* d_ws, size_t ws_size,
                              hipStream_t stream) {
    const float* x      = (const float*)d_in[0];
    const int*   b_rows = (const int*)  d_in[1];
    const int*   b_cols = (const int*)  d_in[2];
    const float* b_vals = (const float*)d_in[3];
    const int*   i_rows = (const int*)  d_in[4];
    const int*   i_cols = (const int*)  d_in[5];
    const float* i_vals = (const float*)d_in[6];

    float* out        = (float*)d_out;
    float* out_item   = out;                              // [N_ITEMS * D]
    float* out_basket = out + (size_t)N_ITEMS * D;        // [N_BASKETS * D]

    char* ws = (char*)d_ws;
    size_t off = 0;
    auto alloc = [&](size_t bytes) -> char* {
        char* p = ws + off;
        off = (off + bytes + 255) & ~(size_t)255;
        return p;
    };
    int*   totB      = (int*)  alloc(NBUK_B * sizeof(int));
    int*   totI      = (int*)  alloc(NBUK_I * sizeof(int));
    int*   baseB     = (int*)  alloc(NBUK_B * sizeof(int));
    int*   baseI     = (int*)  alloc(NBUK_I * sizeof(int));
    int*   rp2B      = (int*)  alloc((NKEYPAD_B + 1) * sizeof(int));
    int*   rp2I      = (int*)  alloc((NKEYPAD_I + 1) * sizeof(int));
    int2*  b_ev      = (int2*) alloc((size_t)NNZ * sizeof(int2));     // 8 MB
    int2*  i_ev      = (int2*) alloc((size_t)NNZ * sizeof(int2));     // 8 MB
    void*  b16_a     = (void*) alloc((size_t)N_BASKETS * D * 2);      // 12.8 MB
    void*  b16_b     = (void*) alloc((size_t)N_BASKETS * D * 2);      // 12.8 MB (L2 result, deferred sum)
    // region R1 (25.6 MB): tables (build) -> x16 (cvt..basketL1) -> cur2 (itemL2..)
    char*  R1        = alloc((size_t)N_ITEMS * D * 2);
    int*   tableB    = (int*)R1;
    int*   tableI    = (int*)(R1 + (size_t)NBLK * NBUK_B * sizeof(int));
    void*  x16       = (void*)R1;
    void*  cur2_16   = (void*)R1;
    // region R2 (25.6 MB): staging (build) -> cur1 (itemL1..)
    char*  R2        = alloc((size_t)N_ITEMS * D * 2);
    int*   stg_keyB  = (int*) R2;
    int2*  stg_cvB   = (int2*)(R2 + (size_t)NNZ * 4);
    int*   stg_keyI  = (int*) (R2 + (size_t)NNZ * 12);
    int2*  stg_cvI   = (int2*)(R2 + (size_t)NNZ * 16);
    void*  cur1_16   = (void*)R2;
    (void)ws_size; (void)in_sizes; (void)n_in; (void)out_size;

    // -------- atomic-free windowed CSR build --------
    k_bucket_hist<<<NBLK, TPB, 0, stream>>>(b_rows, b_cols, i_rows, i_cols,
                                            tableB, tableI);
    k_col_scan<<<NBUK_B + NBUK_I, NBLK, 0, stream>>>(tableB, tableI, totB, totI);
    k_base_scan<<<2, 256, 0, stream>>>(totB, totI, baseB, baseI);
    k_route<<<NBLK, TPB, 0, stream>>>(b_rows, b_cols, b_vals,
                                      i_rows, i_cols, i_vals,
                                      tableB, tableI, baseB, baseI,
                                      stg_keyB, stg_cvB, stg_keyI, stg_cvI);
    k_bucket_sort<<<NBUK_B + NBUK_I, 256, 0, stream>>>(stg_keyB, stg_cvB,
                                                       stg_keyI, stg_cvI,
                                                       baseB, baseI, totB, totI,
                                                       rp2B, rp2I, b_ev, i_ev);
    // x -> fp16 (tables dead after route; x16 aliases them)
    k_cvt<<<2048, 256, 0, stream>>>(reinterpret_cast<const float2*>(x),
                                    reinterpret_cast<__half2*>(x16));

    const int NG_B = (G_B + 3) / 4;   // 1563 blocks
    const int NG_I = (G_I + 3) / 4;   // 3125 blocks

    // -------- layer 1 --------
    // b1 = B @ x; out_basket = b1 (fp32); b16_a = h(b1)
    k_spmm_lds<1, W_B, G_B><<<NG_B, 256, 0, stream>>>(rp2B, b_ev, x16,
        b16_a, out_basket, nullptr, nullptr, nullptr);
    k_spmm_lds<0, W_I, G_I><<<NG_I, 256, 0, stream>>>(rp2I, i_ev, b16_a,
        cur1_16, nullptr, nullptr, nullptr, nullptr);
    // -------- layer 2 --------
    // b2 = B @ cur1 -> b16_b only (sum deferred to L3)
    k_spmm_lds<0, W_B, G_B><<<NG_B, 256, 0, stream>>>(rp2B, b_ev, cur1_16,
        b16_b, nullptr, nullptr, nullptr, nullptr);
    k_spmm_lds<0, W_I, G_I><<<NG_I, 256, 0, stream>>>(rp2I, i_ev, b16_b,
        cur2_16, nullptr, nullptr, nullptr, nullptr);
    // -------- layer 3 --------
    // b3 = B @ cur2; out_basket = (b1_fp32 + f(b16_b) + b3)/3; b16_a = h(b3)
    k_spmm_lds<5, W_B, G_B><<<NG_B, 256, 0, stream>>>(rp2B, b_ev, cur2_16,
        b16_a, out_basket, nullptr, b16_b, nullptr);
    // out_item = (x + f(cur1) + f(cur2) + I @ b3)/4
    k_spmm_lds<4, W_I, G_I><<<NG_I, 256, 0, stream>>>(rp2I, i_ev, b16_a,
        nullptr, out_item, x, cur1_16, cur2_16);
}